// Round 6
// baseline (519.099 us; speedup 1.0000x reference)
//
#include <hip/hip_runtime.h>
#include <hip/hip_bf16.h>

typedef __bf16 bf16_t;
typedef __bf16 bfrag __attribute__((ext_vector_type(8)));
typedef float f4 __attribute__((ext_vector_type(4)));

#define S_LEN 2048
#define HQ_N 32
#define HK_N 8
#define D_DIM 64
#define LOG2E 1.4426950408889634f

// async global->LDS, 16B per lane; LDS dest = wave-uniform base + lane*16
#define GLDS16(gp, lp) __builtin_amdgcn_global_load_lds( \
    (const __attribute__((address_space(1))) void*)(gp), \
    (__attribute__((address_space(3))) void*)(lp), 16, 0, 0)

// ---------------------------------------------------------------------------
// fp32 -> bf16 elementwise convert (x). 8 elems/thread.
// ---------------------------------------------------------------------------
__global__ __launch_bounds__(256) void cvt_bf16(
    const float* __restrict__ src, bf16_t* __restrict__ dst, int n)
{
    int i = (blockIdx.x * 256 + threadIdx.x) * 8;
    if (i >= n) return;
    f4 a = *(const f4*)(src + i);
    f4 b = *(const f4*)(src + i + 4);
    bf16_t o[8];
#pragma unroll
    for (int j = 0; j < 4; ++j) { o[j] = (bf16_t)a[j]; o[4 + j] = (bf16_t)b[j]; }
    *(uint4*)(dst + i) = *(uint4*)o;
}

// ---------------------------------------------------------------------------
// Transpose + cvt: src fp32 [K][N] -> dst bf16 [N][K] (dst rows at row_off).
// ---------------------------------------------------------------------------
__global__ __launch_bounds__(256) void transpose_cvt(
    const float* __restrict__ src, bf16_t* __restrict__ dst,
    int K, int N, int row_off)
{
    __shared__ float T[32][33];
    const int n0 = blockIdx.x * 32;
    const int k0 = blockIdx.y * 32;
    const int tx = threadIdx.x;      // 0..31
    const int ty = threadIdx.y;      // 0..7
#pragma unroll
    for (int i = 0; i < 4; ++i)
        T[ty + 8 * i][tx] = src[(size_t)(k0 + ty + 8 * i) * N + n0 + tx];
    __syncthreads();
#pragma unroll
    for (int i = 0; i < 4; ++i)
        dst[(size_t)(row_off + n0 + ty + 8 * i) * K + k0 + tx] =
            (bf16_t)T[tx][ty + 8 * i];
}

// ---------------------------------------------------------------------------
// bf16 GEMM (m97-class): C[M,N] = A[M,K] * Bt[N,K]^T, glds staging.
// Tile 128x128, BK=64. LDS [128][64] unpadded; XOR chunk-swizzle.
// ---------------------------------------------------------------------------
template<bool OUT_BF16>
__global__ __launch_bounds__(256) void gemm_bt(
    const bf16_t* __restrict__ A, const bf16_t* __restrict__ Bt,
    void* __restrict__ Cv, int M, int N, int K, int ldc)
{
    __shared__ bf16_t As[128][64];
    __shared__ bf16_t Bs[128][64];
    const int tid  = threadIdx.x;
    const int wave = tid >> 6;
    const int lane = tid & 63;
    const int lrow = lane & 15;
    const int quad = lane >> 4;
    const int wm   = (wave >> 1) * 64;
    const int wn   = (wave & 1) * 64;
    const int bm   = blockIdx.y * 128;
    const int bn   = blockIdx.x * 128;

    const int glr = lane >> 3;
    const int glc = (lane & 7) ^ glr;

    const bf16_t* Ab = A  + (size_t)(bm + glr) * K + glc * 8;
    const bf16_t* Bb = Bt + (size_t)(bn + glr) * K + glc * 8;

    f4 acc[4][4];
#pragma unroll
    for (int i = 0; i < 4; ++i)
#pragma unroll
        for (int j = 0; j < 4; ++j)
            acc[i][j] = (f4){0.f, 0.f, 0.f, 0.f};

    for (int k0 = 0; k0 < K; k0 += 64) {
        __syncthreads();
#pragma unroll
        for (int t = 0; t < 4; ++t) {
            const int rb = wave * 8 + t * 32;
            GLDS16(Ab + (size_t)rb * K + k0, &As[rb][0]);
            GLDS16(Bb + (size_t)rb * K + k0, &Bs[rb][0]);
        }
        __syncthreads();

#pragma unroll
        for (int kc = 0; kc < 2; ++kc) {
            bfrag aF[4], bF[4];
#pragma unroll
            for (int i = 0; i < 4; ++i)
                aF[i] = *(const bfrag*)(&As[wm + i * 16 + lrow]
                                           [(((kc << 2) + quad) ^ (lrow & 7)) * 8]);
#pragma unroll
            for (int j = 0; j < 4; ++j)
                bF[j] = *(const bfrag*)(&Bs[wn + j * 16 + lrow]
                                           [(((kc << 2) + quad) ^ (lrow & 7)) * 8]);
#pragma unroll
            for (int i = 0; i < 4; ++i)
#pragma unroll
                for (int j = 0; j < 4; ++j)
                    acc[i][j] = __builtin_amdgcn_mfma_f32_16x16x32_bf16(
                        aF[i], bF[j], acc[i][j], 0, 0, 0);
        }
    }

#pragma unroll
    for (int i = 0; i < 4; ++i)
#pragma unroll
        for (int j = 0; j < 4; ++j)
#pragma unroll
            for (int r = 0; r < 4; ++r) {
                int row = bm + wm + i * 16 + quad * 4 + r;
                int col = bn + wn + j * 16 + lrow;
                if (OUT_BF16)
                    ((bf16_t*)Cv)[(size_t)row * ldc + col] = (bf16_t)acc[i][j][r];
                else
                    ((float*)Cv)[(size_t)row * ldc + col] = acc[i][j][r];
            }
}

// ---------------------------------------------------------------------------
// RoPE in-place on fused qkv bf16 [4096][3072]; q scaled by LOG2E.
// ---------------------------------------------------------------------------
__global__ __launch_bounds__(256) void rope_fused(
    bf16_t* __restrict__ t, const float* __restrict__ cs,
    const float* __restrict__ sn)
{
    int idx = blockIdx.x * 256 + threadIdx.x;   // row-major over [4096][1280]
    int cidx = idx % 1280;
    int row  = idx / 1280;
    int s    = row & (S_LEN - 1);
    int col, d1;
    float scale;
    if (cidx < 1024) {            // q
        d1 = cidx & 31;
        col = (cidx >> 5) * 64 + d1;
        scale = LOG2E;
    } else {                      // k
        int c2 = cidx - 1024;
        d1 = c2 & 31;
        col = 2048 + (c2 >> 5) * 64 + d1;
        scale = 1.0f;
    }
    size_t base = (size_t)row * 3072 + col;
    float t1 = (float)t[base];
    float t2 = (float)t[base + 32];
    float c  = cs[s * 32 + d1];
    float s_ = sn[s * 32 + d1];
    t[base]      = (bf16_t)((t1 * c - t2 * s_) * scale);
    t[base + 32] = (bf16_t)((t2 * c + t1 * s_) * scale);
}

// ---------------------------------------------------------------------------
// MFMA flash attention (R4 formulation: S = Q K^T, O = P V) + REGISTER
// PREFETCH of next K/V tile (software pipeline: global latency hidden
// behind current tile's MFMA/softmax). No-max softmax; q pre-scaled by
// LOG2E -> p = exp2(s + m*LOG2E); l via MFMA with ones B-fragment.
// Numerics identical to round-4 kernel.
// ---------------------------------------------------------------------------
__global__ __launch_bounds__(256, 4) void attn_mfma(
    const bf16_t* __restrict__ qkv, const float* __restrict__ mask,
    bf16_t* __restrict__ o)
{
    __shared__ bf16_t Ks[64][72];    // [key][d]
    __shared__ bf16_t Vt[64][72];    // [d][key]
    __shared__ bf16_t Ps[128][72];   // [row][key], wave-private bands

    const int tid  = threadIdx.x;
    const int wave = tid >> 6;
    const int lane = tid & 63;
    const int lrow = lane & 15;
    const int quad = lane >> 4;
    const int qt   = blockIdx.x;     // 0..15
    const int h    = blockIdx.y;     // 0..31
    const int b    = blockIdx.z;     // 0..1
    const int hk   = h >> 2;
    const int s0   = qt * 128;
    const int wrow = wave * 32;

    // ones B-fragment: B[n][k] = (n==0) -> frag[j] = (lrow==0)
    bfrag vOnes;
#pragma unroll
    for (int j = 0; j < 8; ++j) vOnes[j] = (lrow == 0) ? (bf16_t)1.0f : (bf16_t)0.0f;

    // Q fragments (bf16 direct, already *LOG2E)
    bfrag qf[2][2];
#pragma unroll
    for (int m = 0; m < 2; ++m) {
        const bf16_t* qsrc = qkv + (size_t)(b * S_LEN + s0 + wrow + m * 16 + lrow) * 3072 + h * 64;
#pragma unroll
        for (int c = 0; c < 2; ++c)
            qf[m][c] = *(const bfrag*)(qsrc + c * 32 + quad * 8);
    }

    f4 oacc[2][4], lacc[2];
#pragma unroll
    for (int m = 0; m < 2; ++m) {
        lacc[m] = (f4){0.f, 0.f, 0.f, 0.f};
#pragma unroll
        for (int n = 0; n < 4; ++n) oacc[m][n] = (f4){0.f, 0.f, 0.f, 0.f};
    }

    const int skey = tid >> 2;        // K staging: key 0..63
    const int sdc  = (tid & 3) * 16;  // d chunk
    const int vg   = tid >> 5;        // V staging: key octet 0..7
    const int vp   = tid & 31;        // d pair 0..31

    const bf16_t* kvb = qkv + (size_t)(b * S_LEN) * 3072 + 2048 + hk * 64;

    // ---- prefetch tile 0 into registers ----
    uint4 kr0, kr1;
    unsigned int vw[8];
    {
        const bf16_t* ksrc = kvb + (size_t)skey * 3072 + sdc;
        kr0 = *(const uint4*)(ksrc);
        kr1 = *(const uint4*)(ksrc + 8);
#pragma unroll
        for (int kk = 0; kk < 8; ++kk)
            vw[kk] = *(const unsigned int*)(kvb + 512 + (size_t)(vg * 8 + kk) * 3072 + 2 * vp);
    }

    for (int kt = 0; kt < 32; ++kt) {
        // ---- stage prefetched K/V into LDS ----
        __syncthreads();   // prior iteration's LDS reads complete
        *(uint4*)(&Ks[skey][sdc])     = kr0;
        *(uint4*)(&Ks[skey][sdc + 8]) = kr1;
        {   // V transpose: lane holds 8 keys x 2 dims -> 2 b128 row-writes
            unsigned short lo[8], hi[8];
#pragma unroll
            for (int kk = 0; kk < 8; ++kk) { lo[kk] = vw[kk] & 0xffff; hi[kk] = vw[kk] >> 16; }
            *(uint4*)(&Vt[2 * vp][vg * 8])     = *(uint4*)lo;
            *(uint4*)(&Vt[2 * vp + 1][vg * 8]) = *(uint4*)hi;
        }
        __syncthreads();

        // ---- prefetch NEXT tile into registers (latency hides behind compute) ----
        {
            const int ktn = (kt < 31) ? kt + 1 : 31;
            const bf16_t* ksrc = kvb + (size_t)(ktn * 64 + skey) * 3072 + sdc;
            kr0 = *(const uint4*)(ksrc);
            kr1 = *(const uint4*)(ksrc + 8);
#pragma unroll
            for (int kk = 0; kk < 8; ++kk)
                vw[kk] = *(const unsigned int*)(kvb + 512
                         + (size_t)(ktn * 64 + vg * 8 + kk) * 3072 + 2 * vp);
        }

        // ---- mask loads (scalar; L2/L3-resident) ----
        float mk[2][4][4];
#pragma unroll
        for (int m = 0; m < 2; ++m)
#pragma unroll
            for (int n = 0; n < 4; ++n)
#pragma unroll
                for (int r = 0; r < 4; ++r)
                    mk[m][n][r] = mask[(size_t)(s0 + wrow + m * 16 + quad * 4 + r) * S_LEN
                                       + kt * 64 + n * 16 + lrow];

        // ---- S = Q K^T (already *LOG2E) ----
        bfrag kf[4][2];
#pragma unroll
        for (int n = 0; n < 4; ++n)
#pragma unroll
            for (int c = 0; c < 2; ++c)
                kf[n][c] = *(const bfrag*)(&Ks[n * 16 + lrow][c * 32 + quad * 8]);

        f4 sc[2][4];
#pragma unroll
        for (int m = 0; m < 2; ++m)
#pragma unroll
            for (int n = 0; n < 4; ++n) {
                f4 a = (f4){0.f, 0.f, 0.f, 0.f};
                a = __builtin_amdgcn_mfma_f32_16x16x32_bf16(qf[m][0], kf[n][0], a, 0, 0, 0);
                a = __builtin_amdgcn_mfma_f32_16x16x32_bf16(qf[m][1], kf[n][1], a, 0, 0, 0);
                sc[m][n] = a;
            }

        // ---- p = exp2(s + mask*LOG2E); write P (bf16, wave-private rows) ----
#pragma unroll
        for (int m = 0; m < 2; ++m)
#pragma unroll
            for (int n = 0; n < 4; ++n)
#pragma unroll
                for (int r = 0; r < 4; ++r) {
                    float p = exp2f(fmaf(mk[m][n][r], LOG2E, sc[m][n][r]));
                    Ps[wrow + m * 16 + quad * 4 + r][n * 16 + lrow] = (bf16_t)p;
                }
        // wave-private rows: compiler lgkmcnt ordering suffices, no barrier

        // ---- O += P V ; l += P 1 ----
        bfrag pf[2][2], vf[4][2];
#pragma unroll
        for (int m = 0; m < 2; ++m)
#pragma unroll
            for (int c = 0; c < 2; ++c)
                pf[m][c] = *(const bfrag*)(&Ps[wrow + m * 16 + lrow][c * 32 + quad * 8]);
#pragma unroll
        for (int n = 0; n < 4; ++n)
#pragma unroll
            for (int c = 0; c < 2; ++c)
                vf[n][c] = *(const bfrag*)(&Vt[n * 16 + lrow][c * 32 + quad * 8]);
#pragma unroll
        for (int m = 0; m < 2; ++m) {
#pragma unroll
            for (int n = 0; n < 4; ++n) {
                oacc[m][n] = __builtin_amdgcn_mfma_f32_16x16x32_bf16(pf[m][0], vf[n][0], oacc[m][n], 0, 0, 0);
                oacc[m][n] = __builtin_amdgcn_mfma_f32_16x16x32_bf16(pf[m][1], vf[n][1], oacc[m][n], 0, 0, 0);
            }
            lacc[m] = __builtin_amdgcn_mfma_f32_16x16x32_bf16(pf[m][0], vOnes, lacc[m], 0, 0, 0);
            lacc[m] = __builtin_amdgcn_mfma_f32_16x16x32_bf16(pf[m][1], vOnes, lacc[m], 0, 0, 0);
        }
    }

    // ---- epilogue: broadcast l (col 0 of each quad), write o ----
#pragma unroll
    for (int m = 0; m < 2; ++m)
#pragma unroll
        for (int r = 0; r < 4; ++r) {
            float lv = __shfl(lacc[m][r], lane & 48, 64);
            float inv = 1.f / lv;
            int row = b * S_LEN + s0 + wrow + m * 16 + quad * 4 + r;
#pragma unroll
            for (int n = 0; n < 4; ++n)
                o[(size_t)row * 2048 + h * 64 + n * 16 + lrow] = (bf16_t)(oacc[m][n][r] * inv);
        }
}

// ---------------------------------------------------------------------------
extern "C" void kernel_launch(void* const* d_in, const int* in_sizes, int n_in,
                              void* d_out, int out_size, void* d_ws, size_t ws_size,
                              hipStream_t stream)
{
    const float* x    = (const float*)d_in[0];
    const float* rc   = (const float*)d_in[1];
    const float* rs   = (const float*)d_in[2];
    const float* mask = (const float*)d_in[3];
    const float* Wq   = (const float*)d_in[4];
    const float* Wk   = (const float*)d_in[5];
    const float* Wv   = (const float*)d_in[6];
    const float* Wo   = (const float*)d_in[7];
    float* out = (float*)d_out;

    char* ws = (char*)d_ws;
    bf16_t* qkv = (bf16_t*)(ws);                  // [4096][3072] = 24 MiB
    bf16_t* xb  = (bf16_t*)(ws + (24u << 20));    // [4096][2048] = 16 MiB
    bf16_t* ob  = xb;                             // aliases xb (dead after QKV GEMM)
    bf16_t* Wt3 = (bf16_t*)(ws + (40u << 20));    // [3072][2048] = 12 MiB
    bf16_t* Wot = (bf16_t*)(ws + (52u << 20));    // [2048][2048] =  8 MiB

    const int M = 2 * S_LEN;  // 4096
    dim3 blk(256);

    // pre-pass: cvt x, transpose+cvt weights (Wq/Wk/Wv fused into Wt3)
    cvt_bf16<<<(M * 2048) / (256 * 8), blk, 0, stream>>>(x, xb, M * 2048);
    transpose_cvt<<<dim3(64, 64), dim3(32, 8), 0, stream>>>(Wq, Wt3, 2048, 2048, 0);
    transpose_cvt<<<dim3(16, 64), dim3(32, 8), 0, stream>>>(Wk, Wt3, 2048,  512, 2048);
    transpose_cvt<<<dim3(16, 64), dim3(32, 8), 0, stream>>>(Wv, Wt3, 2048,  512, 2560);
    transpose_cvt<<<dim3(64, 64), dim3(32, 8), 0, stream>>>(Wo, Wot, 2048, 2048, 0);

    // fused QKV projection: qkv[4096][3072] bf16
    gemm_bt<true><<<dim3(3072 / 128, M / 128), blk, 0, stream>>>(
        xb, Wt3, qkv, M, 3072, 2048, 3072);

    // RoPE on q (scaled by LOG2E) and k, in place
    rope_fused<<<(M * 1280) / 256, blk, 0, stream>>>(qkv, rc, rs);

    // attention -> ob[4096][2048] bf16
    attn_mfma<<<dim3(16, 32, 2), blk, 0, stream>>>(qkv, mask, ob);

    // out-projection -> fp32
    gemm_bt<false><<<dim3(2048 / 128, M / 128), blk, 0, stream>>>(
        ob, Wot, out, M, 2048, 2048, 2048);
}

// Round 7
// 426.139 us; speedup vs baseline: 1.2181x; 1.2181x over previous
//
#include <hip/hip_runtime.h>
#include <hip/hip_bf16.h>

typedef __bf16 bf16_t;
typedef __bf16 bfrag __attribute__((ext_vector_type(8)));
typedef float f4 __attribute__((ext_vector_type(4)));

#define S_LEN 2048
#define HQ_N 32
#define HK_N 8
#define D_DIM 64
#define LOG2E 1.4426950408889634f

// async global->LDS, 16B per lane; LDS dest = wave-uniform base + lane*16
#define GLDS16(gp, lp) __builtin_amdgcn_global_load_lds( \
    (const __attribute__((address_space(1))) void*)(gp), \
    (__attribute__((address_space(3))) void*)(lp), 16, 0, 0)

// ---------------------------------------------------------------------------
// fp32 -> bf16 elementwise convert (x). 8 elems/thread.
// ---------------------------------------------------------------------------
__global__ __launch_bounds__(256) void cvt_bf16(
    const float* __restrict__ src, bf16_t* __restrict__ dst, int n)
{
    int i = (blockIdx.x * 256 + threadIdx.x) * 8;
    if (i >= n) return;
    f4 a = *(const f4*)(src + i);
    f4 b = *(const f4*)(src + i + 4);
    bf16_t o[8];
#pragma unroll
    for (int j = 0; j < 4; ++j) { o[j] = (bf16_t)a[j]; o[4 + j] = (bf16_t)b[j]; }
    *(uint4*)(dst + i) = *(uint4*)o;
}

// ---------------------------------------------------------------------------
// Transpose + cvt: src fp32 [K][N] -> dst bf16 [N][K] (dst rows at row_off).
// ---------------------------------------------------------------------------
__global__ __launch_bounds__(256) void transpose_cvt(
    const float* __restrict__ src, bf16_t* __restrict__ dst,
    int K, int N, int row_off)
{
    __shared__ float T[32][33];
    const int n0 = blockIdx.x * 32;
    const int k0 = blockIdx.y * 32;
    const int tx = threadIdx.x;      // 0..31
    const int ty = threadIdx.y;      // 0..7
#pragma unroll
    for (int i = 0; i < 4; ++i)
        T[ty + 8 * i][tx] = src[(size_t)(k0 + ty + 8 * i) * N + n0 + tx];
    __syncthreads();
#pragma unroll
    for (int i = 0; i < 4; ++i)
        dst[(size_t)(row_off + n0 + ty + 8 * i) * K + k0 + tx] =
            (bf16_t)T[tx][ty + 8 * i];
}

// ---------------------------------------------------------------------------
// bf16 GEMM (m97-class): C[M,N] = A[M,K] * Bt[N,K]^T, glds staging.
// Tile 128x128, BK=64. LDS [128][64] unpadded; XOR chunk-swizzle.
// ---------------------------------------------------------------------------
template<bool OUT_BF16>
__global__ __launch_bounds__(256) void gemm_bt(
    const bf16_t* __restrict__ A, const bf16_t* __restrict__ Bt,
    void* __restrict__ Cv, int M, int N, int K, int ldc)
{
    __shared__ bf16_t As[128][64];
    __shared__ bf16_t Bs[128][64];
    const int tid  = threadIdx.x;
    const int wave = tid >> 6;
    const int lane = tid & 63;
    const int lrow = lane & 15;
    const int quad = lane >> 4;
    const int wm   = (wave >> 1) * 64;
    const int wn   = (wave & 1) * 64;
    const int bm   = blockIdx.y * 128;
    const int bn   = blockIdx.x * 128;

    const int glr = lane >> 3;
    const int glc = (lane & 7) ^ glr;

    const bf16_t* Ab = A  + (size_t)(bm + glr) * K + glc * 8;
    const bf16_t* Bb = Bt + (size_t)(bn + glr) * K + glc * 8;

    f4 acc[4][4];
#pragma unroll
    for (int i = 0; i < 4; ++i)
#pragma unroll
        for (int j = 0; j < 4; ++j)
            acc[i][j] = (f4){0.f, 0.f, 0.f, 0.f};

    for (int k0 = 0; k0 < K; k0 += 64) {
        __syncthreads();
#pragma unroll
        for (int t = 0; t < 4; ++t) {
            const int rb = wave * 8 + t * 32;
            GLDS16(Ab + (size_t)rb * K + k0, &As[rb][0]);
            GLDS16(Bb + (size_t)rb * K + k0, &Bs[rb][0]);
        }
        __syncthreads();

#pragma unroll
        for (int kc = 0; kc < 2; ++kc) {
            bfrag aF[4], bF[4];
#pragma unroll
            for (int i = 0; i < 4; ++i)
                aF[i] = *(const bfrag*)(&As[wm + i * 16 + lrow]
                                           [(((kc << 2) + quad) ^ (lrow & 7)) * 8]);
#pragma unroll
            for (int j = 0; j < 4; ++j)
                bF[j] = *(const bfrag*)(&Bs[wn + j * 16 + lrow]
                                           [(((kc << 2) + quad) ^ (lrow & 7)) * 8]);
#pragma unroll
            for (int i = 0; i < 4; ++i)
#pragma unroll
                for (int j = 0; j < 4; ++j)
                    acc[i][j] = __builtin_amdgcn_mfma_f32_16x16x32_bf16(
                        aF[i], bF[j], acc[i][j], 0, 0, 0);
        }
    }

#pragma unroll
    for (int i = 0; i < 4; ++i)
#pragma unroll
        for (int j = 0; j < 4; ++j)
#pragma unroll
            for (int r = 0; r < 4; ++r) {
                int row = bm + wm + i * 16 + quad * 4 + r;
                int col = bn + wn + j * 16 + lrow;
                if (OUT_BF16)
                    ((bf16_t*)Cv)[(size_t)row * ldc + col] = (bf16_t)acc[i][j][r];
                else
                    ((float*)Cv)[(size_t)row * ldc + col] = acc[i][j][r];
            }
}

// ---------------------------------------------------------------------------
// RoPE in-place on fused qkv bf16 [4096][3072]; q scaled by LOG2E.
// ---------------------------------------------------------------------------
__global__ __launch_bounds__(256) void rope_fused(
    bf16_t* __restrict__ t, const float* __restrict__ cs,
    const float* __restrict__ sn)
{
    int idx = blockIdx.x * 256 + threadIdx.x;   // row-major over [4096][1280]
    int cidx = idx % 1280;
    int row  = idx / 1280;
    int s    = row & (S_LEN - 1);
    int col, d1;
    float scale;
    if (cidx < 1024) {            // q
        d1 = cidx & 31;
        col = (cidx >> 5) * 64 + d1;
        scale = LOG2E;
    } else {                      // k
        int c2 = cidx - 1024;
        d1 = c2 & 31;
        col = 2048 + (c2 >> 5) * 64 + d1;
        scale = 1.0f;
    }
    size_t base = (size_t)row * 3072 + col;
    float t1 = (float)t[base];
    float t2 = (float)t[base + 32];
    float c  = cs[s * 32 + d1];
    float s_ = sn[s * 32 + d1];
    t[base]      = (bf16_t)((t1 * c - t2 * s_) * scale);
    t[base + 32] = (bf16_t)((t2 * c + t1 * s_) * scale);
}

// ---------------------------------------------------------------------------
// MFMA flash attention (S = Q K^T, O = P V) + register prefetch of next
// K/V tile. NO occupancy pin (R6's __launch_bounds__(256,4) forced VGPR=64
// -> scratch spills, WRITE_SIZE +20MB, 272us. Let the allocator breathe.)
// No-max softmax; q pre-scaled by LOG2E -> p = exp2(s + m*LOG2E);
// l via MFMA with ones B-fragment. Numerics identical to round-4 kernel.
// ---------------------------------------------------------------------------
__global__ __launch_bounds__(256) void attn_mfma(
    const bf16_t* __restrict__ qkv, const float* __restrict__ mask,
    bf16_t* __restrict__ o)
{
    __shared__ bf16_t Ks[64][72];    // [key][d]
    __shared__ bf16_t Vt[64][72];    // [d][key]
    __shared__ bf16_t Ps[128][72];   // [row][key], wave-private bands

    const int tid  = threadIdx.x;
    const int wave = tid >> 6;
    const int lane = tid & 63;
    const int lrow = lane & 15;
    const int quad = lane >> 4;
    const int qt   = blockIdx.x;     // 0..15
    const int h    = blockIdx.y;     // 0..31
    const int b    = blockIdx.z;     // 0..1
    const int hk   = h >> 2;
    const int s0   = qt * 128;
    const int wrow = wave * 32;

    // ones B-fragment: B[n][k] = (n==0) -> frag[j] = (lrow==0)
    bfrag vOnes;
#pragma unroll
    for (int j = 0; j < 8; ++j) vOnes[j] = (lrow == 0) ? (bf16_t)1.0f : (bf16_t)0.0f;

    // Q fragments (bf16 direct, already *LOG2E)
    bfrag qf[2][2];
#pragma unroll
    for (int m = 0; m < 2; ++m) {
        const bf16_t* qsrc = qkv + (size_t)(b * S_LEN + s0 + wrow + m * 16 + lrow) * 3072 + h * 64;
#pragma unroll
        for (int c = 0; c < 2; ++c)
            qf[m][c] = *(const bfrag*)(qsrc + c * 32 + quad * 8);
    }

    f4 oacc[2][4], lacc[2];
#pragma unroll
    for (int m = 0; m < 2; ++m) {
        lacc[m] = (f4){0.f, 0.f, 0.f, 0.f};
#pragma unroll
        for (int n = 0; n < 4; ++n) oacc[m][n] = (f4){0.f, 0.f, 0.f, 0.f};
    }

    const int skey = tid >> 2;        // K staging: key 0..63
    const int sdc  = (tid & 3) * 16;  // d chunk
    const int vg   = tid >> 5;        // V staging: key octet 0..7
    const int vp   = tid & 31;        // d pair 0..31

    const bf16_t* kvb = qkv + (size_t)(b * S_LEN) * 3072 + 2048 + hk * 64;

    // ---- prefetch tile 0 into registers ----
    uint4 kr0, kr1;
    unsigned int vw[8];
    {
        const bf16_t* ksrc = kvb + (size_t)skey * 3072 + sdc;
        kr0 = *(const uint4*)(ksrc);
        kr1 = *(const uint4*)(ksrc + 8);
#pragma unroll
        for (int kk = 0; kk < 8; ++kk)
            vw[kk] = *(const unsigned int*)(kvb + 512 + (size_t)(vg * 8 + kk) * 3072 + 2 * vp);
    }

    for (int kt = 0; kt < 32; ++kt) {
        // ---- stage prefetched K/V into LDS ----
        __syncthreads();   // prior iteration's LDS reads complete
        *(uint4*)(&Ks[skey][sdc])     = kr0;
        *(uint4*)(&Ks[skey][sdc + 8]) = kr1;
        {   // V transpose: lane holds 8 keys x 2 dims -> 2 b128 row-writes
            unsigned short lo[8], hi[8];
#pragma unroll
            for (int kk = 0; kk < 8; ++kk) { lo[kk] = vw[kk] & 0xffff; hi[kk] = vw[kk] >> 16; }
            *(uint4*)(&Vt[2 * vp][vg * 8])     = *(uint4*)lo;
            *(uint4*)(&Vt[2 * vp + 1][vg * 8]) = *(uint4*)hi;
        }
        __syncthreads();

        // ---- prefetch NEXT tile into registers (latency hides behind compute) ----
        {
            const int ktn = (kt < 31) ? kt + 1 : 31;
            const bf16_t* ksrc = kvb + (size_t)(ktn * 64 + skey) * 3072 + sdc;
            kr0 = *(const uint4*)(ksrc);
            kr1 = *(const uint4*)(ksrc + 8);
#pragma unroll
            for (int kk = 0; kk < 8; ++kk)
                vw[kk] = *(const unsigned int*)(kvb + 512
                         + (size_t)(ktn * 64 + vg * 8 + kk) * 3072 + 2 * vp);
        }

        // ---- mask loads (scalar; L2/L3-resident) ----
        float mk[2][4][4];
#pragma unroll
        for (int m = 0; m < 2; ++m)
#pragma unroll
            for (int n = 0; n < 4; ++n)
#pragma unroll
                for (int r = 0; r < 4; ++r)
                    mk[m][n][r] = mask[(size_t)(s0 + wrow + m * 16 + quad * 4 + r) * S_LEN
                                       + kt * 64 + n * 16 + lrow];

        // ---- S = Q K^T (already *LOG2E) ----
        bfrag kf[4][2];
#pragma unroll
        for (int n = 0; n < 4; ++n)
#pragma unroll
            for (int c = 0; c < 2; ++c)
                kf[n][c] = *(const bfrag*)(&Ks[n * 16 + lrow][c * 32 + quad * 8]);

        f4 sc[2][4];
#pragma unroll
        for (int m = 0; m < 2; ++m)
#pragma unroll
            for (int n = 0; n < 4; ++n) {
                f4 a = (f4){0.f, 0.f, 0.f, 0.f};
                a = __builtin_amdgcn_mfma_f32_16x16x32_bf16(qf[m][0], kf[n][0], a, 0, 0, 0);
                a = __builtin_amdgcn_mfma_f32_16x16x32_bf16(qf[m][1], kf[n][1], a, 0, 0, 0);
                sc[m][n] = a;
            }

        // ---- p = exp2(s + mask*LOG2E); write P (bf16, wave-private rows) ----
#pragma unroll
        for (int m = 0; m < 2; ++m)
#pragma unroll
            for (int n = 0; n < 4; ++n)
#pragma unroll
                for (int r = 0; r < 4; ++r) {
                    float p = exp2f(fmaf(mk[m][n][r], LOG2E, sc[m][n][r]));
                    Ps[wrow + m * 16 + quad * 4 + r][n * 16 + lrow] = (bf16_t)p;
                }
        // wave-private rows: compiler lgkmcnt ordering suffices, no barrier

        // ---- O += P V ; l += P 1 ----
        bfrag pf[2][2], vf[4][2];
#pragma unroll
        for (int m = 0; m < 2; ++m)
#pragma unroll
            for (int c = 0; c < 2; ++c)
                pf[m][c] = *(const bfrag*)(&Ps[wrow + m * 16 + lrow][c * 32 + quad * 8]);
#pragma unroll
        for (int n = 0; n < 4; ++n)
#pragma unroll
            for (int c = 0; c < 2; ++c)
                vf[n][c] = *(const bfrag*)(&Vt[n * 16 + lrow][c * 32 + quad * 8]);
#pragma unroll
        for (int m = 0; m < 2; ++m) {
#pragma unroll
            for (int n = 0; n < 4; ++n) {
                oacc[m][n] = __builtin_amdgcn_mfma_f32_16x16x32_bf16(pf[m][0], vf[n][0], oacc[m][n], 0, 0, 0);
                oacc[m][n] = __builtin_amdgcn_mfma_f32_16x16x32_bf16(pf[m][1], vf[n][1], oacc[m][n], 0, 0, 0);
            }
            lacc[m] = __builtin_amdgcn_mfma_f32_16x16x32_bf16(pf[m][0], vOnes, lacc[m], 0, 0, 0);
            lacc[m] = __builtin_amdgcn_mfma_f32_16x16x32_bf16(pf[m][1], vOnes, lacc[m], 0, 0, 0);
        }
    }

    // ---- epilogue: broadcast l (col 0 of each quad), write o ----
#pragma unroll
    for (int m = 0; m < 2; ++m)
#pragma unroll
        for (int r = 0; r < 4; ++r) {
            float lv = __shfl(lacc[m][r], lane & 48, 64);
            float inv = 1.f / lv;
            int row = b * S_LEN + s0 + wrow + m * 16 + quad * 4 + r;
#pragma unroll
            for (int n = 0; n < 4; ++n)
                o[(size_t)row * 2048 + h * 64 + n * 16 + lrow] = (bf16_t)(oacc[m][n][r] * inv);
        }
}

// ---------------------------------------------------------------------------
extern "C" void kernel_launch(void* const* d_in, const int* in_sizes, int n_in,
                              void* d_out, int out_size, void* d_ws, size_t ws_size,
                              hipStream_t stream)
{
    const float* x    = (const float*)d_in[0];
    const float* rc   = (const float*)d_in[1];
    const float* rs   = (const float*)d_in[2];
    const float* mask = (const float*)d_in[3];
    const float* Wq   = (const float*)d_in[4];
    const float* Wk   = (const float*)d_in[5];
    const float* Wv   = (const float*)d_in[6];
    const float* Wo   = (const float*)d_in[7];
    float* out = (float*)d_out;

    char* ws = (char*)d_ws;
    bf16_t* qkv = (bf16_t*)(ws);                  // [4096][3072] = 24 MiB
    bf16_t* xb  = (bf16_t*)(ws + (24u << 20));    // [4096][2048] = 16 MiB
    bf16_t* ob  = xb;                             // aliases xb (dead after QKV GEMM)
    bf16_t* Wt3 = (bf16_t*)(ws + (40u << 20));    // [3072][2048] = 12 MiB
    bf16_t* Wot = (bf16_t*)(ws + (52u << 20));    // [2048][2048] =  8 MiB

    const int M = 2 * S_LEN;  // 4096
    dim3 blk(256);

    // pre-pass: cvt x, transpose+cvt weights (Wq/Wk/Wv fused into Wt3)
    cvt_bf16<<<(M * 2048) / (256 * 8), blk, 0, stream>>>(x, xb, M * 2048);
    transpose_cvt<<<dim3(64, 64), dim3(32, 8), 0, stream>>>(Wq, Wt3, 2048, 2048, 0);
    transpose_cvt<<<dim3(16, 64), dim3(32, 8), 0, stream>>>(Wk, Wt3, 2048,  512, 2048);
    transpose_cvt<<<dim3(16, 64), dim3(32, 8), 0, stream>>>(Wv, Wt3, 2048,  512, 2560);
    transpose_cvt<<<dim3(64, 64), dim3(32, 8), 0, stream>>>(Wo, Wot, 2048, 2048, 0);

    // fused QKV projection: qkv[4096][3072] bf16
    gemm_bt<true><<<dim3(3072 / 128, M / 128), blk, 0, stream>>>(
        xb, Wt3, qkv, M, 3072, 2048, 3072);

    // RoPE on q (scaled by LOG2E) and k, in place
    rope_fused<<<(M * 1280) / 256, blk, 0, stream>>>(qkv, rc, rs);

    // attention -> ob[4096][2048] bf16
    attn_mfma<<<dim3(16, 32, 2), blk, 0, stream>>>(qkv, mask, ob);

    // out-projection -> fp32
    gemm_bt<false><<<dim3(2048 / 128, M / 128), blk, 0, stream>>>(
        ob, Wot, out, M, 2048, 2048, 2048);
}